// Round 1
// baseline (2155.052 us; speedup 1.0000x reference)
//
#include <hip/hip_runtime.h>

#define NN 8192
#define NE 65536

typedef __attribute__((ext_vector_type(8))) __bf16 bf16x8;
typedef __attribute__((ext_vector_type(4))) float f32x4;

__device__ __forceinline__ float bf2f(unsigned short s) {
  union { unsigned u; float f; } z; z.u = ((unsigned)s) << 16; return z.f;
}
__device__ __forceinline__ unsigned short f2bf(float f) {
  union { float f; unsigned u; } z; z.f = f;
  return (unsigned short)((z.u + 0x7FFFu + ((z.u >> 16) & 1u)) >> 16);
}

__global__ __launch_bounds__(256) void k_zero_i32(int* p, int n) {
  int t = blockIdx.x * 256 + threadIdx.x;
  if (t < n) p[t] = 0;
}

// pack W (K x 128 row-major fp32) -> WT (128 x Kpad row-major bf16), zero-padded K..Kpad
__device__ __forceinline__ void packone(int t, const float* src, unsigned short* dst, int K, int Kpad) {
  int n = t / Kpad, k = t % Kpad;
  dst[n * Kpad + k] = (k < K) ? f2bf(src[k * 128 + n]) : (unsigned short)0;
}

__global__ __launch_bounds__(256) void k_pack_all(
    const float* ve1, unsigned short* tve1, const float* ve2, unsigned short* tve2,
    const float* ee1, unsigned short* tee1, const float* ee2, unsigned short* tee2,
    const float* em1, unsigned short* tem1, const float* em2, unsigned short* tem2,
    const float* nm1, unsigned short* tnm1, const float* nm2, unsigned short* tnm2,
    const float* dc1, unsigned short* tdc1) {
  int t = blockIdx.x * 256 + threadIdx.x;
  if (t < 4096) packone(t, ve1, tve1, 8, 32);
  else if (t < 20480) packone(t - 4096, ve2, tve2, 128, 128);
  else if (t < 24576) packone(t - 20480, ee1, tee1, 6, 32);
  else if (t < 40960) packone(t - 24576, ee2, tee2, 128, 128);
  else if (t < 90112) packone(t - 40960, em1, tem1, 384, 384);
  else if (t < 106496) packone(t - 90112, em2, tem2, 128, 128);
  else if (t < 139264) packone(t - 106496, nm1, tnm1, 256, 256);
  else if (t < 155648) packone(t - 139264, nm2, tnm2, 128, 128);
  else if (t < 172032) packone(t - 155648, dc1, tdc1, 128, 128);
}

__global__ __launch_bounds__(256) void k_prep_nodes(const int* __restrict__ sn,
                                                    const float* __restrict__ vf,
                                                    unsigned short* __restrict__ X) {
  int n = blockIdx.x * 256 + threadIdx.x;
  if (n >= NN) return;
  unsigned short* row = &X[(size_t)n * 32];
  int s = sn[n];
  row[0] = f2bf(s == 0 ? 1.f : 0.f);
  row[1] = f2bf(s == 1 ? 1.f : 0.f);
#pragma unroll
  for (int j = 0; j < 6; j++) row[2 + j] = f2bf(vf[n * 6 + j]);
#pragma unroll
  for (int j = 8; j < 32; j++) row[j] = 0;
}

__global__ __launch_bounds__(256) void k_prep_edges(const int* __restrict__ eidx,
                                                    const float* __restrict__ wc,
                                                    const float* __restrict__ mc,
                                                    unsigned short* __restrict__ X,
                                                    int* __restrict__ cnt) {
  int t = blockIdx.x * 256 + threadIdx.x;
  if (t >= NE) return;
  int r = eidx[t], c = eidx[NE + t];
  float ex = wc[c * 2] - wc[r * 2];
  float ey = wc[c * 2 + 1] - wc[r * 2 + 1];
  float mx = mc[c * 2] - mc[r * 2];
  float my = mc[c * 2 + 1] - mc[r * 2 + 1];
  unsigned short* row = &X[(size_t)t * 32];
  row[0] = f2bf(ex); row[1] = f2bf(ey); row[2] = f2bf(sqrtf(ex * ex + ey * ey));
  row[3] = f2bf(mx); row[4] = f2bf(my); row[5] = f2bf(sqrtf(mx * mx + my * my));
#pragma unroll
  for (int j = 6; j < 32; j++) row[j] = 0;
  atomicAdd(&cnt[r], 1);
}

__global__ __launch_bounds__(1024) void k_scan(const int* __restrict__ cnt,
                                               int* __restrict__ offs,
                                               int* __restrict__ cursor) {
  __shared__ int sd[1024];
  int tid = threadIdx.x;
  int loc[8];
  int s = 0;
#pragma unroll
  for (int i = 0; i < 8; i++) { loc[i] = s; s += cnt[tid * 8 + i]; }
  sd[tid] = s;
  __syncthreads();
  for (int o = 1; o < 1024; o <<= 1) {
    int vv = 0;
    if (tid >= o) vv = sd[tid - o];
    __syncthreads();
    sd[tid] += vv;
    __syncthreads();
  }
  int base = (tid == 0) ? 0 : sd[tid - 1];
#pragma unroll
  for (int i = 0; i < 8; i++) {
    int o = base + loc[i];
    offs[tid * 8 + i] = o;
    cursor[tid * 8 + i] = o;
  }
  if (tid == 1023) offs[8192] = sd[1023];
}

__global__ __launch_bounds__(256) void k_fill(const int* __restrict__ eidx,
                                              int* __restrict__ cursor,
                                              int* __restrict__ elist) {
  int t = blockIdx.x * 256 + threadIdx.x;
  if (t >= NE) return;
  int r = eidx[t];
  int pos = atomicAdd(&cursor[r], 1);
  elist[pos] = t;
}

// ---------------- fused MLP(+gather/agg/residual/LN) kernel -------------------
// 64 rows per block, 256 threads = 4 waves, wave w owns rows [16w,16w+16).
// GEMM via mfma_f32_16x16x32_bf16. A/B frags: lane l -> row/col (l&15), k-group (l>>4).
// C/D frags: col = lane&15, row = (lane>>4)*4 + reg.
enum { MODE_ENC = 0, MODE_EDGE = 1, MODE_NODE = 2 };

template <int KT, int MODE>
__global__ __launch_bounds__(256) void k_mlp(
    const unsigned short* __restrict__ Xbuf,
    const unsigned short* __restrict__ vbuf,
    const unsigned short* __restrict__ ebuf,
    const int* __restrict__ eidx,
    const int* __restrict__ offs, const int* __restrict__ elist,
    const unsigned short* __restrict__ W1T, const float* __restrict__ b1,
    const unsigned short* __restrict__ W2T, const float* __restrict__ b2,
    const float* __restrict__ lng, const float* __restrict__ lnb,
    unsigned short* __restrict__ outbuf) {
  constexpr int K = KT * 32;
  constexpr int XS = K + 8;  // bf16 elements per LDS row (pad keeps 16B align, breaks bank pow2)
  __shared__ __align__(16) unsigned short Xt[64 * XS];
  __shared__ __align__(16) unsigned short H1[64 * 136];
  __shared__ int lidx[128];
  const int tid = threadIdx.x;
  const int row0 = blockIdx.x * 64;

  if (MODE == MODE_EDGE) {
    if (tid < 64) lidx[tid] = eidx[row0 + tid];             // row endpoint
    else if (tid < 128) lidx[tid] = eidx[NE + row0 + (tid - 64)];  // col endpoint
    __syncthreads();
  }

  constexpr int CH = K / 8;  // 16B chunks per row
  for (int i = tid; i < 64 * CH; i += 256) {
    int r = i / CH, c = i % CH;
    uint4 val;
    if (MODE == MODE_ENC) {
      val = *(const uint4*)&Xbuf[(size_t)(row0 + r) * K + c * 8];
    } else if (MODE == MODE_EDGE) {
      const unsigned short* src;
      if (c < 16) src = &vbuf[(size_t)lidx[r] * 128 + c * 8];
      else if (c < 32) src = &vbuf[(size_t)lidx[64 + r] * 128 + (c - 16) * 8];
      else src = &ebuf[(size_t)(row0 + r) * 128 + (c - 32) * 8];
      val = *(const uint4*)src;
    } else {  // MODE_NODE: [v | agg]; agg computed in-place from CSR
      if (c < 16) {
        val = *(const uint4*)&vbuf[(size_t)(row0 + r) * 128 + c * 8];
      } else {
        int n = row0 + r;
        int beg = offs[n], end = offs[n + 1];
        float acc[8];
#pragma unroll
        for (int j = 0; j < 8; j++) acc[j] = 0.f;
        for (int q = beg; q < end; ++q) {
          uint4 ev = *(const uint4*)&ebuf[(size_t)elist[q] * 128 + (c - 16) * 8];
          const unsigned short* es = (const unsigned short*)&ev;
#pragma unroll
          for (int j = 0; j < 8; j++) acc[j] += bf2f(es[j]);
        }
        union { uint4 u; unsigned short s[8]; } tmp;
#pragma unroll
        for (int j = 0; j < 8; j++) tmp.s[j] = f2bf(acc[j]);
        val = tmp.u;
      }
    }
    *(uint4*)&Xt[r * XS + c * 8] = val;
  }
  __syncthreads();

  const int lane = tid & 63;
  const int wid = tid >> 6;
  const int l4 = lane >> 4;
  const int l15 = lane & 15;

  // GEMM1: (16 x K) @ (K x 128) per wave
  f32x4 acc1[8] = {};
#pragma unroll
  for (int kt = 0; kt < KT; kt++) {
    bf16x8 a = *(const bf16x8*)&Xt[(wid * 16 + l15) * XS + kt * 32 + l4 * 8];
#pragma unroll
    for (int ct = 0; ct < 8; ct++) {
      bf16x8 b = *(const bf16x8*)&W1T[(size_t)(ct * 16 + l15) * K + kt * 32 + l4 * 8];
      acc1[ct] = __builtin_amdgcn_mfma_f32_16x16x32_bf16(a, b, acc1[ct], 0, 0, 0);
    }
  }
  // bias + relu -> H1 (bf16, wave-private rows)
#pragma unroll
  for (int ct = 0; ct < 8; ct++) {
    int colc = ct * 16 + l15;
    float bb = b1[colc];
#pragma unroll
    for (int r = 0; r < 4; r++) {
      float h = acc1[ct][r] + bb;
      h = h > 0.f ? h : 0.f;
      H1[(wid * 16 + l4 * 4 + r) * 136 + colc] = f2bf(h);
    }
  }
  // GEMM2: (16 x 128) @ (128 x 128) per wave (same-wave LDS RAW -> hw-ordered)
  f32x4 acc2[8] = {};
#pragma unroll
  for (int kt = 0; kt < 4; kt++) {
    bf16x8 a = *(const bf16x8*)&H1[(wid * 16 + l15) * 136 + kt * 32 + l4 * 8];
#pragma unroll
    for (int ct = 0; ct < 8; ct++) {
      bf16x8 b = *(const bf16x8*)&W2T[(size_t)(ct * 16 + l15) * 128 + kt * 32 + l4 * 8];
      acc2[ct] = __builtin_amdgcn_mfma_f32_16x16x32_bf16(a, b, acc2[ct], 0, 0, 0);
    }
  }
  // bias2 + residual + LayerNorm (row stats via xor-shuffle over lane bits 0..3)
  float vals[8][4];
  float s0[4] = {0, 0, 0, 0}, s1[4] = {0, 0, 0, 0};
#pragma unroll
  for (int ct = 0; ct < 8; ct++) {
    int colc = ct * 16 + l15;
    float bb = b2[colc];
#pragma unroll
    for (int r = 0; r < 4; r++) {
      float x = acc2[ct][r] + bb;
      if (MODE == MODE_EDGE) x += bf2f(Xt[(wid * 16 + l4 * 4 + r) * XS + 256 + colc]);
      if (MODE == MODE_NODE) x += bf2f(Xt[(wid * 16 + l4 * 4 + r) * XS + colc]);
      vals[ct][r] = x;
      s0[r] += x;
      s1[r] += x * x;
    }
  }
#pragma unroll
  for (int m = 1; m < 16; m <<= 1) {
#pragma unroll
    for (int r = 0; r < 4; r++) {
      s0[r] += __shfl_xor(s0[r], m, 64);
      s1[r] += __shfl_xor(s1[r], m, 64);
    }
  }
  float mean[4], rstd[4];
#pragma unroll
  for (int r = 0; r < 4; r++) {
    mean[r] = s0[r] * (1.f / 128.f);
    float var = s1[r] * (1.f / 128.f) - mean[r] * mean[r];
    rstd[r] = rsqrtf(var + 1e-5f);
  }
#pragma unroll
  for (int ct = 0; ct < 8; ct++) {
    int colc = ct * 16 + l15;
    float g = lng[colc], bb = lnb[colc];
#pragma unroll
    for (int r = 0; r < 4; r++) {
      float y = (vals[ct][r] - mean[r]) * rstd[r] * g + bb;
      H1[(wid * 16 + l4 * 4 + r) * 136 + colc] = f2bf(y);  // reuse H1 as out-stage
    }
  }
  // coalesced copy-out of the wave's 16 rows
#pragma unroll
  for (int i = 0; i < 4; i++) {
    int j = lane + i * 64;
    int r = j >> 4, ch = j & 15;
    *(uint4*)&outbuf[(size_t)(row0 + wid * 16 + r) * 128 + ch * 8] =
        *(const uint4*)&H1[(wid * 16 + r) * 136 + ch * 8];
  }
}

__global__ __launch_bounds__(256) void k_decode(const unsigned short* __restrict__ vbuf,
                                                const unsigned short* __restrict__ W1T,
                                                const float* __restrict__ b1,
                                                const float* __restrict__ w2,
                                                const float* __restrict__ b2,
                                                float* __restrict__ out) {
  __shared__ __align__(16) unsigned short Xt[64 * 136];
  __shared__ __align__(16) unsigned short H1[64 * 136];
  const int tid = threadIdx.x;
  const int row0 = blockIdx.x * 64;
  for (int i = tid; i < 64 * 16; i += 256) {
    int r = i >> 4, c = i & 15;
    *(uint4*)&Xt[r * 136 + c * 8] = *(const uint4*)&vbuf[(size_t)(row0 + r) * 128 + c * 8];
  }
  __syncthreads();
  const int lane = tid & 63;
  const int wid = tid >> 6;
  const int l4 = lane >> 4;
  const int l15 = lane & 15;
  f32x4 acc1[8] = {};
#pragma unroll
  for (int kt = 0; kt < 4; kt++) {
    bf16x8 a = *(const bf16x8*)&Xt[(wid * 16 + l15) * 136 + kt * 32 + l4 * 8];
#pragma unroll
    for (int ct = 0; ct < 8; ct++) {
      bf16x8 b = *(const bf16x8*)&W1T[(size_t)(ct * 16 + l15) * 128 + kt * 32 + l4 * 8];
      acc1[ct] = __builtin_amdgcn_mfma_f32_16x16x32_bf16(a, b, acc1[ct], 0, 0, 0);
    }
  }
#pragma unroll
  for (int ct = 0; ct < 8; ct++) {
    int colc = ct * 16 + l15;
    float bb = b1[colc];
#pragma unroll
    for (int r = 0; r < 4; r++) {
      float h = acc1[ct][r] + bb;
      h = h > 0.f ? h : 0.f;
      H1[(wid * 16 + l4 * 4 + r) * 136 + colc] = f2bf(h);
    }
  }
  __syncthreads();
  for (int i = tid; i < 64 * 6; i += 256) {
    int r = i / 6, o = i % 6;
    float s = b2[o];
    for (int k = 0; k < 128; k++) s += bf2f(H1[r * 136 + k]) * w2[k * 6 + o];
    out[(size_t)(row0 + r) * 6 + o] = s;
  }
}

extern "C" void kernel_launch(void* const* d_in, const int* in_sizes, int n_in,
                              void* d_out, int out_size, void* d_ws, size_t ws_size,
                              hipStream_t stream) {
  (void)in_sizes; (void)n_in; (void)out_size; (void)ws_size;
  const float* wc = (const float*)d_in[0];
  const float* vf = (const float*)d_in[1];
  const float* mc = (const float*)d_in[2];
  const float* ve_w1 = (const float*)d_in[3];
  const float* ve_b1 = (const float*)d_in[4];
  const float* ve_w2 = (const float*)d_in[5];
  const float* ve_b2 = (const float*)d_in[6];
  const float* ee_w1 = (const float*)d_in[7];
  const float* ee_b1 = (const float*)d_in[8];
  const float* ee_w2 = (const float*)d_in[9];
  const float* ee_b2 = (const float*)d_in[10];
  const float* enc_g = (const float*)d_in[11];
  const float* enc_b = (const float*)d_in[12];
  const float* em_w1 = (const float*)d_in[13];
  const float* em_b1 = (const float*)d_in[14];
  const float* em_w2 = (const float*)d_in[15];
  const float* em_b2 = (const float*)d_in[16];
  const float* em_g = (const float*)d_in[17];
  const float* em_lb = (const float*)d_in[18];
  const float* nm_w1 = (const float*)d_in[19];
  const float* nm_b1 = (const float*)d_in[20];
  const float* nm_w2 = (const float*)d_in[21];
  const float* nm_b2 = (const float*)d_in[22];
  const float* nm_g = (const float*)d_in[23];
  const float* nm_lb = (const float*)d_in[24];
  const float* dec_w1 = (const float*)d_in[25];
  const float* dec_b1 = (const float*)d_in[26];
  const float* dec_w2 = (const float*)d_in[27];
  const float* dec_b2 = (const float*)d_in[28];
  const int* eidx = (const int*)d_in[29];
  const int* sn = (const int*)d_in[30];
  float* dout = (float*)d_out;

  char* w = (char*)d_ws;
  size_t off = 0;
  auto alloc = [&](size_t bytes) {
    char* p = w + off;
    off += (bytes + 255) & ~(size_t)255;
    return p;
  };
  unsigned short* v = (unsigned short*)alloc((size_t)NN * 128 * 2);
  unsigned short* e = (unsigned short*)alloc((size_t)NE * 128 * 2);
  unsigned short* Xve = (unsigned short*)alloc((size_t)NN * 32 * 2);
  unsigned short* Xee = (unsigned short*)alloc((size_t)NE * 32 * 2);
  unsigned short* tve1 = (unsigned short*)alloc(128 * 32 * 2);
  unsigned short* tve2 = (unsigned short*)alloc(128 * 128 * 2);
  unsigned short* tee1 = (unsigned short*)alloc(128 * 32 * 2);
  unsigned short* tee2 = (unsigned short*)alloc(128 * 128 * 2);
  unsigned short* tem1 = (unsigned short*)alloc(128 * 384 * 2);
  unsigned short* tem2 = (unsigned short*)alloc(128 * 128 * 2);
  unsigned short* tnm1 = (unsigned short*)alloc(128 * 256 * 2);
  unsigned short* tnm2 = (unsigned short*)alloc(128 * 128 * 2);
  unsigned short* tdc1 = (unsigned short*)alloc(128 * 128 * 2);
  int* cnt = (int*)alloc(NN * 4);
  int* offsb = (int*)alloc((NN + 1) * 4);
  int* cursor = (int*)alloc(NN * 4);
  int* elist = (int*)alloc((size_t)NE * 4);

  k_zero_i32<<<32, 256, 0, stream>>>(cnt, NN);
  k_pack_all<<<672, 256, 0, stream>>>(ve_w1, tve1, ve_w2, tve2, ee_w1, tee1, ee_w2, tee2,
                                      em_w1, tem1, em_w2, tem2, nm_w1, tnm1, nm_w2, tnm2,
                                      dec_w1, tdc1);
  k_prep_nodes<<<32, 256, 0, stream>>>(sn, vf, Xve);
  k_prep_edges<<<256, 256, 0, stream>>>(eidx, wc, mc, Xee, cnt);
  k_scan<<<1, 1024, 0, stream>>>(cnt, offsb, cursor);
  k_fill<<<256, 256, 0, stream>>>(eidx, cursor, elist);

  k_mlp<1, MODE_ENC><<<128, 256, 0, stream>>>(Xve, nullptr, nullptr, nullptr, nullptr, nullptr,
                                              tve1, ve_b1, tve2, ve_b2, enc_g, enc_b, v);
  k_mlp<1, MODE_ENC><<<1024, 256, 0, stream>>>(Xee, nullptr, nullptr, nullptr, nullptr, nullptr,
                                               tee1, ee_b1, tee2, ee_b2, enc_g, enc_b, e);
  for (int s = 0; s < 15; ++s) {
    k_mlp<12, MODE_EDGE><<<1024, 256, 0, stream>>>(nullptr, v, e, eidx, nullptr, nullptr,
                                                   tem1, em_b1, tem2, em_b2, em_g, em_lb, e);
    k_mlp<8, MODE_NODE><<<128, 256, 0, stream>>>(nullptr, v, e, nullptr, offsb, elist,
                                                 tnm1, nm_b1, tnm2, nm_b2, nm_g, nm_lb, v);
  }
  k_decode<<<128, 256, 0, stream>>>(v, tdc1, dec_b1, dec_w2, dec_b2, dout);
}

// Round 2
// 1058.200 us; speedup vs baseline: 2.0365x; 2.0365x over previous
//
#include <hip/hip_runtime.h>

#define NN 8192
#define NE 65536

typedef __attribute__((ext_vector_type(8))) __bf16 bf16x8;
typedef __attribute__((ext_vector_type(4))) float f32x4;

__device__ __forceinline__ float bf2f(unsigned short s) {
  union { unsigned u; float f; } z; z.u = ((unsigned)s) << 16; return z.f;
}
__device__ __forceinline__ unsigned short f2bf(float f) {
  union { float f; unsigned u; } z; z.f = f;
  return (unsigned short)((z.u + 0x7FFFu + ((z.u >> 16) & 1u)) >> 16);
}

__global__ __launch_bounds__(256) void k_zero_i32(int* p, int n) {
  int t = blockIdx.x * 256 + threadIdx.x;
  if (t < n) p[t] = 0;
}

// pack W (K x 128 row-major fp32) -> slab-major bf16: [K/32][128][32], zero-padded K..Kpad
__device__ __forceinline__ void packone(int t, const float* src, unsigned short* dst, int K, int Kpad) {
  (void)Kpad;
  int s = t >> 12;         // slab = 4096 elements (128 n x 32 k)
  int rem = t & 4095;
  int n = rem >> 5, k2 = rem & 31;
  int k = s * 32 + k2;
  dst[t] = (k < K) ? f2bf(src[k * 128 + n]) : (unsigned short)0;
}

__global__ __launch_bounds__(256) void k_pack_all(
    const float* ve1, unsigned short* tve1, const float* ve2, unsigned short* tve2,
    const float* ee1, unsigned short* tee1, const float* ee2, unsigned short* tee2,
    const float* em1, unsigned short* tem1, const float* em2, unsigned short* tem2,
    const float* nm1, unsigned short* tnm1, const float* nm2, unsigned short* tnm2,
    const float* dc1, unsigned short* tdc1) {
  int t = blockIdx.x * 256 + threadIdx.x;
  if (t < 4096) packone(t, ve1, tve1, 8, 32);
  else if (t < 20480) packone(t - 4096, ve2, tve2, 128, 128);
  else if (t < 24576) packone(t - 20480, ee1, tee1, 6, 32);
  else if (t < 40960) packone(t - 24576, ee2, tee2, 128, 128);
  else if (t < 90112) packone(t - 40960, em1, tem1, 384, 384);
  else if (t < 106496) packone(t - 90112, em2, tem2, 128, 128);
  else if (t < 139264) packone(t - 106496, nm1, tnm1, 256, 256);
  else if (t < 155648) packone(t - 139264, nm2, tnm2, 128, 128);
  else if (t < 172032) packone(t - 155648, dc1, tdc1, 128, 128);
}

__global__ __launch_bounds__(256) void k_prep_nodes(const int* __restrict__ sn,
                                                    const float* __restrict__ vf,
                                                    unsigned short* __restrict__ X) {
  int n = blockIdx.x * 256 + threadIdx.x;
  if (n >= NN) return;
  unsigned short* row = &X[(size_t)n * 32];
  int s = sn[n];
  row[0] = f2bf(s == 0 ? 1.f : 0.f);
  row[1] = f2bf(s == 1 ? 1.f : 0.f);
#pragma unroll
  for (int j = 0; j < 6; j++) row[2 + j] = f2bf(vf[n * 6 + j]);
#pragma unroll
  for (int j = 8; j < 32; j++) row[j] = 0;
}

__global__ __launch_bounds__(256) void k_prep_edges(const int* __restrict__ eidx,
                                                    const float* __restrict__ wc,
                                                    const float* __restrict__ mc,
                                                    unsigned short* __restrict__ X,
                                                    int* __restrict__ cnt) {
  int t = blockIdx.x * 256 + threadIdx.x;
  if (t >= NE) return;
  int r = eidx[t], c = eidx[NE + t];
  float ex = wc[c * 2] - wc[r * 2];
  float ey = wc[c * 2 + 1] - wc[r * 2 + 1];
  float mx = mc[c * 2] - mc[r * 2];
  float my = mc[c * 2 + 1] - mc[r * 2 + 1];
  unsigned short* row = &X[(size_t)t * 32];
  row[0] = f2bf(ex); row[1] = f2bf(ey); row[2] = f2bf(sqrtf(ex * ex + ey * ey));
  row[3] = f2bf(mx); row[4] = f2bf(my); row[5] = f2bf(sqrtf(mx * mx + my * my));
#pragma unroll
  for (int j = 6; j < 32; j++) row[j] = 0;
  atomicAdd(&cnt[r], 1);
}

__global__ __launch_bounds__(1024) void k_scan(const int* __restrict__ cnt,
                                               int* __restrict__ offs,
                                               int* __restrict__ cursor) {
  __shared__ int sd[1024];
  int tid = threadIdx.x;
  int loc[8];
  int s = 0;
#pragma unroll
  for (int i = 0; i < 8; i++) { loc[i] = s; s += cnt[tid * 8 + i]; }
  sd[tid] = s;
  __syncthreads();
  for (int o = 1; o < 1024; o <<= 1) {
    int vv = 0;
    if (tid >= o) vv = sd[tid - o];
    __syncthreads();
    sd[tid] += vv;
    __syncthreads();
  }
  int base = (tid == 0) ? 0 : sd[tid - 1];
#pragma unroll
  for (int i = 0; i < 8; i++) {
    int o = base + loc[i];
    offs[tid * 8 + i] = o;
    cursor[tid * 8 + i] = o;
  }
  if (tid == 1023) offs[8192] = sd[1023];
}

__global__ __launch_bounds__(256) void k_fill(const int* __restrict__ eidx,
                                              int* __restrict__ cursor,
                                              int* __restrict__ elist) {
  int t = blockIdx.x * 256 + threadIdx.x;
  if (t >= NE) return;
  int r = eidx[t];
  int pos = atomicAdd(&cursor[r], 1);
  elist[pos] = t;
}

// ------------------ fused MLP v2: direct A-gather + LDS weight slabs ---------
// MODE 1 = edge ([v[row]|v[col]|e] @ W1, residual e), MODE 2 = node ([v|agg] @ W1, residual v)
// wave owns 16 rows; A-frag: row = lane&15, k-chunk = (lane>>4)*8. C/D: col=lane&15, row=(lane>>4)*4+reg.
// Weights slab-major [K/32][128][32]; two slabs (16KB) staged in LDS per barrier pair.
template <int KT, int MODE, int WAVES>
__global__ __launch_bounds__(WAVES * 64) void k_mlp2(
    const unsigned short* __restrict__ vbuf,
    const unsigned short* __restrict__ ebuf,
    const int* __restrict__ eidx,
    const int* __restrict__ offs, const int* __restrict__ elist,
    const unsigned short* __restrict__ W1T, const float* __restrict__ b1,
    const unsigned short* __restrict__ W2T, const float* __restrict__ b2,
    const float* __restrict__ lng, const float* __restrict__ lnb,
    unsigned short* __restrict__ outbuf) {
  constexpr int BS = WAVES * 64;
  constexpr int MB = WAVES * 16;
  __shared__ __align__(16) unsigned short H1[MB * 136];  // node: agg staging, then H1, then out-stage
  __shared__ __align__(16) unsigned short Wb[8192];      // 16KB = 2 weight slabs
  const int tid = threadIdx.x;
  const int lane = tid & 63, wid = tid >> 6;
  const int l4 = lane >> 4, l15 = lane & 15;
  const int row0 = blockIdx.x * MB;
  const int myrow = row0 + wid * 16 + l15;

  // ---- A-fragment preload (per-lane global gathers; long-latency, issued first) ----
  bf16x8 af[KT];
  if (MODE == 1) {
    int ridx = eidx[myrow];
    int cidx = eidx[NE + myrow];
#pragma unroll
    for (int kt = 0; kt < 4; kt++)
      af[kt] = *(const bf16x8*)&vbuf[(size_t)ridx * 128 + kt * 32 + l4 * 8];
#pragma unroll
    for (int kt = 0; kt < 4; kt++)
      af[4 + kt] = *(const bf16x8*)&vbuf[(size_t)cidx * 128 + kt * 32 + l4 * 8];
#pragma unroll
    for (int kt = 0; kt < 4; kt++)
      af[8 + kt] = *(const bf16x8*)&ebuf[(size_t)myrow * 128 + kt * 32 + l4 * 8];
  } else {
#pragma unroll
    for (int kt = 0; kt < 4; kt++)
      af[kt] = *(const bf16x8*)&vbuf[(size_t)myrow * 128 + kt * 32 + l4 * 8];
    // agg = segment_sum(e) over CSR, staged to LDS then fragment-loaded
    for (int i = tid; i < MB * 16; i += BS) {
      int r = i >> 4, c = i & 15;
      int n = row0 + r;
      int beg = offs[n], end = offs[n + 1];
      float acc[8] = {0.f, 0.f, 0.f, 0.f, 0.f, 0.f, 0.f, 0.f};
      for (int q = beg; q < end; ++q) {
        uint4 ev = *(const uint4*)&ebuf[(size_t)elist[q] * 128 + c * 8];
        const unsigned short* es = (const unsigned short*)&ev;
#pragma unroll
        for (int j = 0; j < 8; j++) acc[j] += bf2f(es[j]);
      }
      union { uint4 u; unsigned short s[8]; } tmp;
#pragma unroll
      for (int j = 0; j < 8; j++) tmp.s[j] = f2bf(acc[j]);
      *(uint4*)&H1[r * 136 + c * 8] = tmp.u;
    }
    __syncthreads();
#pragma unroll
    for (int kt = 0; kt < 4; kt++)
      af[4 + kt] = *(const bf16x8*)&H1[(wid * 16 + l15) * 136 + kt * 32 + l4 * 8];
  }

  auto stageW = [&](const unsigned short* src) {
    const uint4* s4 = (const uint4*)src;
    uint4* d4 = (uint4*)Wb;
#pragma unroll
    for (int u = 0; u < 1024 / BS; ++u) d4[tid + u * BS] = s4[tid + u * BS];
  };

  // ---- GEMM1: (MB x K) @ (K x 128), weights from LDS slabs ----
  f32x4 acc1[8] = {};
#pragma unroll
  for (int g = 0; g < KT / 2; ++g) {
    stageW(&W1T[g * 8192]);
    __syncthreads();
#pragma unroll
    for (int s2 = 0; s2 < 2; ++s2) {
#pragma unroll
      for (int ct = 0; ct < 8; ct++) {
        bf16x8 b = *(const bf16x8*)&Wb[s2 * 4096 + (ct * 16 + l15) * 32 + l4 * 8];
        acc1[ct] = __builtin_amdgcn_mfma_f32_16x16x32_bf16(af[g * 2 + s2], b, acc1[ct], 0, 0, 0);
      }
    }
    __syncthreads();
  }

  // bias + relu -> H1 (wave-private rows), then GEMM2 A-frags
#pragma unroll
  for (int ct = 0; ct < 8; ct++) {
    float bb = b1[ct * 16 + l15];
#pragma unroll
    for (int r = 0; r < 4; r++) {
      float h = fmaxf(acc1[ct][r] + bb, 0.f);
      H1[(wid * 16 + l4 * 4 + r) * 136 + ct * 16 + l15] = f2bf(h);
    }
  }
  bf16x8 hf[4];
#pragma unroll
  for (int kt = 0; kt < 4; kt++)
    hf[kt] = *(const bf16x8*)&H1[(wid * 16 + l15) * 136 + kt * 32 + l4 * 8];

  // ---- GEMM2: (MB x 128) @ (128 x 128) ----
  f32x4 acc2[8] = {};
#pragma unroll
  for (int g = 0; g < 2; ++g) {
    stageW(&W2T[g * 8192]);
    __syncthreads();
#pragma unroll
    for (int s2 = 0; s2 < 2; ++s2) {
#pragma unroll
      for (int ct = 0; ct < 8; ct++) {
        bf16x8 b = *(const bf16x8*)&Wb[s2 * 4096 + (ct * 16 + l15) * 32 + l4 * 8];
        acc2[ct] = __builtin_amdgcn_mfma_f32_16x16x32_bf16(hf[g * 2 + s2], b, acc2[ct], 0, 0, 0);
      }
    }
    __syncthreads();
  }

  // ---- bias2 + residual + LayerNorm (f32 stats in regs, xor-shuffle over lane bits 0..3) ----
  const unsigned short* resid = (MODE == 1) ? ebuf : vbuf;
  float vals[8][4];
  float s0[4] = {0, 0, 0, 0}, s1[4] = {0, 0, 0, 0};
#pragma unroll
  for (int ct = 0; ct < 8; ct++) {
    float bb = b2[ct * 16 + l15];
#pragma unroll
    for (int r = 0; r < 4; r++) {
      int rr = row0 + wid * 16 + l4 * 4 + r;
      float x = acc2[ct][r] + bb + bf2f(resid[(size_t)rr * 128 + ct * 16 + l15]);
      vals[ct][r] = x;
      s0[r] += x;
      s1[r] += x * x;
    }
  }
#pragma unroll
  for (int m = 1; m < 16; m <<= 1) {
#pragma unroll
    for (int r = 0; r < 4; r++) {
      s0[r] += __shfl_xor(s0[r], m, 64);
      s1[r] += __shfl_xor(s1[r], m, 64);
    }
  }
  float mean[4], rstd[4];
#pragma unroll
  for (int r = 0; r < 4; r++) {
    mean[r] = s0[r] * (1.f / 128.f);
    float var = s1[r] * (1.f / 128.f) - mean[r] * mean[r];
    rstd[r] = rsqrtf(var + 1e-5f);
  }
#pragma unroll
  for (int ct = 0; ct < 8; ct++) {
    int colc = ct * 16 + l15;
    float g = lng[colc], bb = lnb[colc];
#pragma unroll
    for (int r = 0; r < 4; r++) {
      float y = (vals[ct][r] - mean[r]) * rstd[r] * g + bb;
      H1[(wid * 16 + l4 * 4 + r) * 136 + colc] = f2bf(y);  // out-stage (wave-private)
    }
  }
#pragma unroll
  for (int i = 0; i < 4; i++) {
    int j = lane + i * 64;
    int r = j >> 4, ch = j & 15;
    *(uint4*)&outbuf[(size_t)(row0 + wid * 16 + r) * 128 + ch * 8] =
        *(const uint4*)&H1[(wid * 16 + r) * 136 + ch * 8];
  }
}

// ------------------ encoder MLP (K=32 padded input, no residual) -------------
__global__ __launch_bounds__(256) void k_enc(const unsigned short* __restrict__ Xbuf,
                                             const unsigned short* __restrict__ W1T,
                                             const float* __restrict__ b1,
                                             const unsigned short* __restrict__ W2T,
                                             const float* __restrict__ b2,
                                             const float* __restrict__ lng,
                                             const float* __restrict__ lnb,
                                             unsigned short* __restrict__ outbuf) {
  __shared__ __align__(16) unsigned short Xt[64 * 40];
  __shared__ __align__(16) unsigned short H1[64 * 136];
  const int tid = threadIdx.x;
  const int row0 = blockIdx.x * 64;
  {
    int r = tid >> 2, c = tid & 3;
    *(uint4*)&Xt[r * 40 + c * 8] = *(const uint4*)&Xbuf[(size_t)(row0 + r) * 32 + c * 8];
  }
  __syncthreads();
  const int lane = tid & 63, wid = tid >> 6;
  const int l4 = lane >> 4, l15 = lane & 15;

  f32x4 acc1[8] = {};
  bf16x8 a = *(const bf16x8*)&Xt[(wid * 16 + l15) * 40 + l4 * 8];
#pragma unroll
  for (int ct = 0; ct < 8; ct++) {
    bf16x8 b = *(const bf16x8*)&W1T[(ct * 16 + l15) * 32 + l4 * 8];
    acc1[ct] = __builtin_amdgcn_mfma_f32_16x16x32_bf16(a, b, acc1[ct], 0, 0, 0);
  }
#pragma unroll
  for (int ct = 0; ct < 8; ct++) {
    float bb = b1[ct * 16 + l15];
#pragma unroll
    for (int r = 0; r < 4; r++) {
      float h = fmaxf(acc1[ct][r] + bb, 0.f);
      H1[(wid * 16 + l4 * 4 + r) * 136 + ct * 16 + l15] = f2bf(h);
    }
  }
  bf16x8 hf[4];
#pragma unroll
  for (int kt = 0; kt < 4; kt++)
    hf[kt] = *(const bf16x8*)&H1[(wid * 16 + l15) * 136 + kt * 32 + l4 * 8];
  f32x4 acc2[8] = {};
#pragma unroll
  for (int kt = 0; kt < 4; kt++) {
#pragma unroll
    for (int ct = 0; ct < 8; ct++) {
      bf16x8 b = *(const bf16x8*)&W2T[kt * 4096 + (ct * 16 + l15) * 32 + l4 * 8];
      acc2[kt == 0 ? ct : ct] = acc2[ct];  // no-op to keep shape clear
      acc2[ct] = __builtin_amdgcn_mfma_f32_16x16x32_bf16(hf[kt], b, acc2[ct], 0, 0, 0);
    }
  }
  float vals[8][4];
  float s0[4] = {0, 0, 0, 0}, s1[4] = {0, 0, 0, 0};
#pragma unroll
  for (int ct = 0; ct < 8; ct++) {
    float bb = b2[ct * 16 + l15];
#pragma unroll
    for (int r = 0; r < 4; r++) {
      float x = acc2[ct][r] + bb;
      vals[ct][r] = x;
      s0[r] += x;
      s1[r] += x * x;
    }
  }
#pragma unroll
  for (int m = 1; m < 16; m <<= 1) {
#pragma unroll
    for (int r = 0; r < 4; r++) {
      s0[r] += __shfl_xor(s0[r], m, 64);
      s1[r] += __shfl_xor(s1[r], m, 64);
    }
  }
  float mean[4], rstd[4];
#pragma unroll
  for (int r = 0; r < 4; r++) {
    mean[r] = s0[r] * (1.f / 128.f);
    float var = s1[r] * (1.f / 128.f) - mean[r] * mean[r];
    rstd[r] = rsqrtf(var + 1e-5f);
  }
#pragma unroll
  for (int ct = 0; ct < 8; ct++) {
    int colc = ct * 16 + l15;
    float g = lng[colc], bb = lnb[colc];
#pragma unroll
    for (int r = 0; r < 4; r++) {
      float y = (vals[ct][r] - mean[r]) * rstd[r] * g + bb;
      H1[(wid * 16 + l4 * 4 + r) * 136 + colc] = f2bf(y);
    }
  }
#pragma unroll
  for (int i = 0; i < 4; i++) {
    int j = lane + i * 64;
    int r = j >> 4, ch = j & 15;
    *(uint4*)&outbuf[(size_t)(row0 + wid * 16 + r) * 128 + ch * 8] =
        *(const uint4*)&H1[(wid * 16 + r) * 136 + ch * 8];
  }
}

__global__ __launch_bounds__(256) void k_decode(const unsigned short* __restrict__ vbuf,
                                                const unsigned short* __restrict__ W1T,
                                                const float* __restrict__ b1,
                                                const float* __restrict__ w2,
                                                const float* __restrict__ b2,
                                                float* __restrict__ out) {
  __shared__ __align__(16) unsigned short Xt[64 * 136];
  __shared__ __align__(16) unsigned short H1[64 * 136];
  const int tid = threadIdx.x;
  const int row0 = blockIdx.x * 64;
  for (int i = tid; i < 64 * 16; i += 256) {
    int r = i >> 4, c = i & 15;
    *(uint4*)&Xt[r * 136 + c * 8] = *(const uint4*)&vbuf[(size_t)(row0 + r) * 128 + c * 8];
  }
  __syncthreads();
  const int lane = tid & 63, wid = tid >> 6;
  const int l4 = lane >> 4, l15 = lane & 15;
  f32x4 acc1[8] = {};
#pragma unroll
  for (int kt = 0; kt < 4; kt++) {
    bf16x8 a = *(const bf16x8*)&Xt[(wid * 16 + l15) * 136 + kt * 32 + l4 * 8];
#pragma unroll
    for (int ct = 0; ct < 8; ct++) {
      bf16x8 b = *(const bf16x8*)&W1T[kt * 4096 + (ct * 16 + l15) * 32 + l4 * 8];
      acc1[ct] = __builtin_amdgcn_mfma_f32_16x16x32_bf16(a, b, acc1[ct], 0, 0, 0);
    }
  }
#pragma unroll
  for (int ct = 0; ct < 8; ct++) {
    float bb = b1[ct * 16 + l15];
#pragma unroll
    for (int r = 0; r < 4; r++) {
      float h = fmaxf(acc1[ct][r] + bb, 0.f);
      H1[(wid * 16 + l4 * 4 + r) * 136 + ct * 16 + l15] = f2bf(h);
    }
  }
  __syncthreads();
  for (int i = tid; i < 64 * 6; i += 256) {
    int r = i / 6, o = i % 6;
    float s = b2[o];
    for (int k = 0; k < 128; k++) s += bf2f(H1[r * 136 + k]) * w2[k * 6 + o];
    out[(size_t)(row0 + r) * 6 + o] = s;
  }
}

extern "C" void kernel_launch(void* const* d_in, const int* in_sizes, int n_in,
                              void* d_out, int out_size, void* d_ws, size_t ws_size,
                              hipStream_t stream) {
  (void)in_sizes; (void)n_in; (void)out_size; (void)ws_size;
  const float* wc = (const float*)d_in[0];
  const float* vf = (const float*)d_in[1];
  const float* mc = (const float*)d_in[2];
  const float* ve_w1 = (const float*)d_in[3];
  const float* ve_b1 = (const float*)d_in[4];
  const float* ve_w2 = (const float*)d_in[5];
  const float* ve_b2 = (const float*)d_in[6];
  const float* ee_w1 = (const float*)d_in[7];
  const float* ee_b1 = (const float*)d_in[8];
  const float* ee_w2 = (const float*)d_in[9];
  const float* ee_b2 = (const float*)d_in[10];
  const float* enc_g = (const float*)d_in[11];
  const float* enc_b = (const float*)d_in[12];
  const float* em_w1 = (const float*)d_in[13];
  const float* em_b1 = (const float*)d_in[14];
  const float* em_w2 = (const float*)d_in[15];
  const float* em_b2 = (const float*)d_in[16];
  const float* em_g = (const float*)d_in[17];
  const float* em_lb = (const float*)d_in[18];
  const float* nm_w1 = (const float*)d_in[19];
  const float* nm_b1 = (const float*)d_in[20];
  const float* nm_w2 = (const float*)d_in[21];
  const float* nm_b2 = (const float*)d_in[22];
  const float* nm_g = (const float*)d_in[23];
  const float* nm_lb = (const float*)d_in[24];
  const float* dec_w1 = (const float*)d_in[25];
  const float* dec_b1 = (const float*)d_in[26];
  const float* dec_w2 = (const float*)d_in[27];
  const float* dec_b2 = (const float*)d_in[28];
  const int* eidx = (const int*)d_in[29];
  const int* sn = (const int*)d_in[30];
  float* dout = (float*)d_out;

  char* w = (char*)d_ws;
  size_t off = 0;
  auto alloc = [&](size_t bytes) {
    char* p = w + off;
    off += (bytes + 255) & ~(size_t)255;
    return p;
  };
  unsigned short* v = (unsigned short*)alloc((size_t)NN * 128 * 2);
  unsigned short* e = (unsigned short*)alloc((size_t)NE * 128 * 2);
  unsigned short* Xve = (unsigned short*)alloc((size_t)NN * 32 * 2);
  unsigned short* Xee = (unsigned short*)alloc((size_t)NE * 32 * 2);
  unsigned short* tve1 = (unsigned short*)alloc(128 * 32 * 2);
  unsigned short* tve2 = (unsigned short*)alloc(128 * 128 * 2);
  unsigned short* tee1 = (unsigned short*)alloc(128 * 32 * 2);
  unsigned short* tee2 = (unsigned short*)alloc(128 * 128 * 2);
  unsigned short* tem1 = (unsigned short*)alloc(128 * 384 * 2);
  unsigned short* tem2 = (unsigned short*)alloc(128 * 128 * 2);
  unsigned short* tnm1 = (unsigned short*)alloc(128 * 256 * 2);
  unsigned short* tnm2 = (unsigned short*)alloc(128 * 128 * 2);
  unsigned short* tdc1 = (unsigned short*)alloc(128 * 128 * 2);
  int* cnt = (int*)alloc(NN * 4);
  int* offsb = (int*)alloc((NN + 1) * 4);
  int* cursor = (int*)alloc(NN * 4);
  int* elist = (int*)alloc((size_t)NE * 4);

  k_zero_i32<<<32, 256, 0, stream>>>(cnt, NN);
  k_pack_all<<<672, 256, 0, stream>>>(ve_w1, tve1, ve_w2, tve2, ee_w1, tee1, ee_w2, tee2,
                                      em_w1, tem1, em_w2, tem2, nm_w1, tnm1, nm_w2, tnm2,
                                      dec_w1, tdc1);
  k_prep_nodes<<<32, 256, 0, stream>>>(sn, vf, Xve);
  k_prep_edges<<<256, 256, 0, stream>>>(eidx, wc, mc, Xee, cnt);
  k_scan<<<1, 1024, 0, stream>>>(cnt, offsb, cursor);
  k_fill<<<256, 256, 0, stream>>>(eidx, cursor, elist);

  k_enc<<<128, 256, 0, stream>>>(Xve, tve1, ve_b1, tve2, ve_b2, enc_g, enc_b, v);
  k_enc<<<1024, 256, 0, stream>>>(Xee, tee1, ee_b1, tee2, ee_b2, enc_g, enc_b, e);
  for (int s = 0; s < 15; ++s) {
    k_mlp2<12, 1, 4><<<1024, 256, 0, stream>>>(v, e, eidx, nullptr, nullptr,
                                               tem1, em_b1, tem2, em_b2, em_g, em_lb, e);
    k_mlp2<8, 2, 2><<<256, 128, 0, stream>>>(v, e, nullptr, offsb, elist,
                                             tnm1, nm_b1, tnm2, nm_b2, nm_g, nm_lb, v);
  }
  k_decode<<<128, 256, 0, stream>>>(v, tdc1, dec_b1, dec_w2, dec_b2, dout);
}

// Round 3
// 827.160 us; speedup vs baseline: 2.6054x; 1.2793x over previous
//
#include <hip/hip_runtime.h>

#define NN 8192
#define NE 65536

typedef __attribute__((ext_vector_type(8))) __bf16 bf16x8;
typedef __attribute__((ext_vector_type(4))) float f32x4;

typedef __attribute__((address_space(1))) const void* as1_cvoid;
typedef __attribute__((address_space(3))) void* as3_void;

__device__ __forceinline__ float bf2f(unsigned short s) {
  union { unsigned u; float f; } z; z.u = ((unsigned)s) << 16; return z.f;
}
__device__ __forceinline__ unsigned short f2bf(float f) {
  union { float f; unsigned u; } z; z.f = f;
  return (unsigned short)((z.u + 0x7FFFu + ((z.u >> 16) & 1u)) >> 16);
}
__device__ __forceinline__ void gl_lds16(const void* g, void* l) {
  __builtin_amdgcn_global_load_lds((as1_cvoid)g, (as3_void)l, 16, 0, 0);
}

__global__ __launch_bounds__(256) void k_zero_i32(int* p, int n) {
  int t = blockIdx.x * 256 + threadIdx.x;
  if (t < n) p[t] = 0;
}

// pack W (K x 128 row-major fp32) -> slab-major bf16: [K/32][128][32], zero-padded K..Kpad
__device__ __forceinline__ void packone(int t, const float* src, unsigned short* dst, int K, int Kpad) {
  (void)Kpad;
  int s = t >> 12;
  int rem = t & 4095;
  int n = rem >> 5, k2 = rem & 31;
  int k = s * 32 + k2;
  dst[t] = (k < K) ? f2bf(src[k * 128 + n]) : (unsigned short)0;
}

__global__ __launch_bounds__(256) void k_pack_all(
    const float* ve1, unsigned short* tve1, const float* ve2, unsigned short* tve2,
    const float* ee1, unsigned short* tee1, const float* ee2, unsigned short* tee2,
    const float* em1, unsigned short* tem1, const float* em2, unsigned short* tem2,
    const float* nm1, unsigned short* tnm1, const float* nm2, unsigned short* tnm2,
    const float* dc1, unsigned short* tdc1) {
  int t = blockIdx.x * 256 + threadIdx.x;
  if (t < 4096) packone(t, ve1, tve1, 8, 32);
  else if (t < 20480) packone(t - 4096, ve2, tve2, 128, 128);
  else if (t < 24576) packone(t - 20480, ee1, tee1, 6, 32);
  else if (t < 40960) packone(t - 24576, ee2, tee2, 128, 128);
  else if (t < 90112) packone(t - 40960, em1, tem1, 384, 384);
  else if (t < 106496) packone(t - 90112, em2, tem2, 128, 128);
  else if (t < 139264) packone(t - 106496, nm1, tnm1, 256, 256);
  else if (t < 155648) packone(t - 139264, nm2, tnm2, 128, 128);
  else if (t < 172032) packone(t - 155648, dc1, tdc1, 128, 128);
}

__global__ __launch_bounds__(256) void k_prep_nodes(const int* __restrict__ sn,
                                                    const float* __restrict__ vf,
                                                    unsigned short* __restrict__ X) {
  int n = blockIdx.x * 256 + threadIdx.x;
  if (n >= NN) return;
  unsigned short* row = &X[(size_t)n * 32];
  int s = sn[n];
  row[0] = f2bf(s == 0 ? 1.f : 0.f);
  row[1] = f2bf(s == 1 ? 1.f : 0.f);
#pragma unroll
  for (int j = 0; j < 6; j++) row[2 + j] = f2bf(vf[n * 6 + j]);
#pragma unroll
  for (int j = 8; j < 32; j++) row[j] = 0;
}

__global__ __launch_bounds__(256) void k_prep_edges(const int* __restrict__ eidx,
                                                    const float* __restrict__ wc,
                                                    const float* __restrict__ mc,
                                                    unsigned short* __restrict__ X,
                                                    int* __restrict__ cnt) {
  int t = blockIdx.x * 256 + threadIdx.x;
  if (t >= NE) return;
  int r = eidx[t], c = eidx[NE + t];
  float ex = wc[c * 2] - wc[r * 2];
  float ey = wc[c * 2 + 1] - wc[r * 2 + 1];
  float mx = mc[c * 2] - mc[r * 2];
  float my = mc[c * 2 + 1] - mc[r * 2 + 1];
  unsigned short* row = &X[(size_t)t * 32];
  row[0] = f2bf(ex); row[1] = f2bf(ey); row[2] = f2bf(sqrtf(ex * ex + ey * ey));
  row[3] = f2bf(mx); row[4] = f2bf(my); row[5] = f2bf(sqrtf(mx * mx + my * my));
#pragma unroll
  for (int j = 6; j < 32; j++) row[j] = 0;
  atomicAdd(&cnt[r], 1);
}

__global__ __launch_bounds__(1024) void k_scan(const int* __restrict__ cnt,
                                               int* __restrict__ offs,
                                               int* __restrict__ cursor) {
  __shared__ int sd[1024];
  int tid = threadIdx.x;
  int loc[8];
  int s = 0;
#pragma unroll
  for (int i = 0; i < 8; i++) { loc[i] = s; s += cnt[tid * 8 + i]; }
  sd[tid] = s;
  __syncthreads();
  for (int o = 1; o < 1024; o <<= 1) {
    int vv = 0;
    if (tid >= o) vv = sd[tid - o];
    __syncthreads();
    sd[tid] += vv;
    __syncthreads();
  }
  int base = (tid == 0) ? 0 : sd[tid - 1];
#pragma unroll
  for (int i = 0; i < 8; i++) {
    int o = base + loc[i];
    offs[tid * 8 + i] = o;
    cursor[tid * 8 + i] = o;
  }
  if (tid == 1023) offs[8192] = sd[1023];
}

__global__ __launch_bounds__(256) void k_fill(const int* __restrict__ eidx,
                                              int* __restrict__ cursor,
                                              int* __restrict__ elist) {
  int t = blockIdx.x * 256 + threadIdx.x;
  if (t >= NE) return;
  int r = eidx[t];
  int pos = atomicAdd(&cursor[r], 1);
  elist[pos] = t;
}

// ---------------- edge step: 512 blocks x 256 threads, 128 rows/block --------
// wave owns 32 rows (2 groups of 16). Weight slab-pairs (16KB) double-buffered
// in LDS via global_load_lds, issued immediately after the barrier that frees
// the buffer (one barrier per phase). A-frags prefetched one phase ahead.
__global__ __launch_bounds__(256) void k_edge(
    const unsigned short* __restrict__ vbuf,
    unsigned short* __restrict__ ebuf,
    const int* __restrict__ eidx,
    const unsigned short* __restrict__ W1T, const float* __restrict__ b1,
    const unsigned short* __restrict__ W2T, const float* __restrict__ b2,
    const float* __restrict__ lng, const float* __restrict__ lnb) {
  __shared__ __align__(16) unsigned short H1[128 * 136];
  __shared__ __align__(16) unsigned short Wb[2][8192];
  const int tid = threadIdx.x;
  const int lane = tid & 63, wid = tid >> 6;
  const int l4 = lane >> 4, l15 = lane & 15;
  const int row0 = blockIdx.x * 128;
  const int r0 = row0 + wid * 32 + l15;
  const int r1 = r0 + 16;
  const int ridx0 = eidx[r0], ridx1 = eidx[r1];
  const int cidx0 = eidx[NE + r0], cidx1 = eidx[NE + r1];

  auto stage = [&](int b, const unsigned short* src) {
#pragma unroll
    for (int u = 0; u < 4; ++u)
      gl_lds16(src + (u * 256 + tid) * 8, &Wb[b][(u * 256 + tid) * 8]);
  };
  auto asrc = [&](int g, int s) -> const unsigned short* {
    int rr = g ? r1 : r0;
    int ri = g ? ridx1 : ridx0;
    int ci = g ? cidx1 : cidx0;
    if (s < 4) return &vbuf[(size_t)ri * 128 + s * 32 + l4 * 8];
    if (s < 8) return &vbuf[(size_t)ci * 128 + (s - 4) * 32 + l4 * 8];
    return &ebuf[(size_t)rr * 128 + (s - 8) * 32 + l4 * 8];
  };

  stage(0, W1T);
  bf16x8 cur[2][2], nxt[2][2];
#pragma unroll
  for (int g = 0; g < 2; g++)
#pragma unroll
    for (int s = 0; s < 2; s++) cur[g][s] = *(const bf16x8*)asrc(g, s);

  // ---- GEMM1: 6 slab-pair phases ----
  f32x4 acc1[2][8] = {};
#pragma unroll
  for (int p = 0; p < 6; ++p) {
    __syncthreads();  // Wb[p&1] staged & visible; Wb[(p+1)&1] free to overwrite
    if (p < 5) {
      stage((p + 1) & 1, W1T + (p + 1) * 8192);
#pragma unroll
      for (int g = 0; g < 2; g++)
#pragma unroll
        for (int s = 0; s < 2; s++) nxt[g][s] = *(const bf16x8*)asrc(g, 2 * (p + 1) + s);
    } else {
      stage((p + 1) & 1, W2T);  // W2 pair 0
    }
#pragma unroll
    for (int s = 0; s < 2; s++)
#pragma unroll
      for (int ct = 0; ct < 8; ct++) {
        bf16x8 b = *(const bf16x8*)&Wb[p & 1][(s * 128 + ct * 16 + l15) * 32 + l4 * 8];
        acc1[0][ct] = __builtin_amdgcn_mfma_f32_16x16x32_bf16(cur[0][s], b, acc1[0][ct], 0, 0, 0);
        acc1[1][ct] = __builtin_amdgcn_mfma_f32_16x16x32_bf16(cur[1][s], b, acc1[1][ct], 0, 0, 0);
      }
    if (p < 5) {
#pragma unroll
      for (int g = 0; g < 2; g++)
#pragma unroll
        for (int s = 0; s < 2; s++) cur[g][s] = nxt[g][s];
    }
  }

  // ---- bias1 + relu -> H1 (wave-private rows), load GEMM2 A-frags ----
#pragma unroll
  for (int g = 0; g < 2; g++)
#pragma unroll
    for (int ct = 0; ct < 8; ct++) {
      float bb = b1[ct * 16 + l15];
#pragma unroll
      for (int r = 0; r < 4; r++) {
        float h = fmaxf(acc1[g][ct][r] + bb, 0.f);
        H1[(wid * 32 + g * 16 + l4 * 4 + r) * 136 + ct * 16 + l15] = f2bf(h);
      }
    }
  bf16x8 hf[2][4];
#pragma unroll
  for (int g = 0; g < 2; g++)
#pragma unroll
    for (int kt = 0; kt < 4; kt++)
      hf[g][kt] = *(const bf16x8*)&H1[(wid * 32 + g * 16 + l15) * 136 + kt * 32 + l4 * 8];

  // ---- GEMM2: 2 slab-pair phases ----
  f32x4 acc2[2][8] = {};
#pragma unroll
  for (int p = 6; p < 8; ++p) {
    __syncthreads();
    if (p < 7) stage((p + 1) & 1, W2T + 8192);
#pragma unroll
    for (int s = 0; s < 2; s++)
#pragma unroll
      for (int ct = 0; ct < 8; ct++) {
        bf16x8 b = *(const bf16x8*)&Wb[p & 1][(s * 128 + ct * 16 + l15) * 32 + l4 * 8];
        acc2[0][ct] = __builtin_amdgcn_mfma_f32_16x16x32_bf16(hf[0][(p - 6) * 2 + s], b, acc2[0][ct], 0, 0, 0);
        acc2[1][ct] = __builtin_amdgcn_mfma_f32_16x16x32_bf16(hf[1][(p - 6) * 2 + s], b, acc2[1][ct], 0, 0, 0);
      }
  }

  // ---- bias2 + residual(e) + LayerNorm, per group ----
#pragma unroll
  for (int g = 0; g < 2; g++) {
    float s0[4] = {0, 0, 0, 0}, s1v[4] = {0, 0, 0, 0};
#pragma unroll
    for (int ct = 0; ct < 8; ct++) {
      float bb = b2[ct * 16 + l15];
#pragma unroll
      for (int r = 0; r < 4; r++) {
        int rr = row0 + wid * 32 + g * 16 + l4 * 4 + r;
        float x = acc2[g][ct][r] + bb + bf2f(ebuf[(size_t)rr * 128 + ct * 16 + l15]);
        acc2[g][ct][r] = x;
        s0[r] += x;
        s1v[r] += x * x;
      }
    }
#pragma unroll
    for (int m = 1; m < 16; m <<= 1)
#pragma unroll
      for (int r = 0; r < 4; r++) {
        s0[r] += __shfl_xor(s0[r], m, 64);
        s1v[r] += __shfl_xor(s1v[r], m, 64);
      }
#pragma unroll
    for (int ct = 0; ct < 8; ct++) {
      float gsc = lng[ct * 16 + l15], bsc = lnb[ct * 16 + l15];
#pragma unroll
      for (int r = 0; r < 4; r++) {
        float mean = s0[r] * (1.f / 128.f);
        float var = s1v[r] * (1.f / 128.f) - mean * mean;
        float y = (acc2[g][ct][r] - mean) * rsqrtf(var + 1e-5f) * gsc + bsc;
        H1[(wid * 32 + g * 16 + l4 * 4 + r) * 136 + ct * 16 + l15] = f2bf(y);
      }
    }
  }
  // coalesced store of the wave's 32 rows
#pragma unroll
  for (int i = 0; i < 8; i++) {
    int j = lane + i * 64;
    int r = j >> 4, ch = j & 15;
    *(uint4*)&ebuf[(size_t)(row0 + wid * 32 + r) * 128 + ch * 8] =
        *(const uint4*)&H1[(wid * 32 + r) * 136 + ch * 8];
  }
}

// ---------------- node step: 256 blocks x 128 threads, 32 rows/block ---------
__global__ __launch_bounds__(128) void k_node(
    unsigned short* __restrict__ vbuf,
    const unsigned short* __restrict__ ebuf,
    const int* __restrict__ offs, const int* __restrict__ elist,
    const unsigned short* __restrict__ W1T, const float* __restrict__ b1,
    const unsigned short* __restrict__ W2T, const float* __restrict__ b2,
    const float* __restrict__ lng, const float* __restrict__ lnb) {
  __shared__ __align__(16) unsigned short AggH[32 * 136];  // agg staging, then H1
  __shared__ __align__(16) unsigned short Wb[2][8192];
  const int tid = threadIdx.x;
  const int lane = tid & 63, wid = tid >> 6;  // 2 waves
  const int l4 = lane >> 4, l15 = lane & 15;
  const int row0 = blockIdx.x * 32;
  const int myrow = row0 + wid * 16 + l15;

  auto stage = [&](int b, const unsigned short* src) {
#pragma unroll
    for (int u = 0; u < 8; ++u)
      gl_lds16(src + (u * 128 + tid) * 8, &Wb[b][(u * 128 + tid) * 8]);
  };

  stage(0, W1T);
  bf16x8 av[4];
#pragma unroll
  for (int kt = 0; kt < 4; kt++)
    av[kt] = *(const bf16x8*)&vbuf[(size_t)myrow * 128 + kt * 32 + l4 * 8];

  // CSR segment-sum of e into AggH (unrolled x2: two independent load chains)
  for (int i = tid; i < 32 * 16; i += 128) {
    int r = i >> 4, c = i & 15;
    int n = row0 + r;
    int beg = offs[n], end = offs[n + 1];
    float a0[8] = {0, 0, 0, 0, 0, 0, 0, 0}, a1[8] = {0, 0, 0, 0, 0, 0, 0, 0};
    int q = beg;
    for (; q + 2 <= end; q += 2) {
      uint4 u0 = *(const uint4*)&ebuf[(size_t)elist[q] * 128 + c * 8];
      uint4 u1 = *(const uint4*)&ebuf[(size_t)elist[q + 1] * 128 + c * 8];
      const unsigned short* p0 = (const unsigned short*)&u0;
      const unsigned short* p1 = (const unsigned short*)&u1;
#pragma unroll
      for (int j = 0; j < 8; j++) { a0[j] += bf2f(p0[j]); a1[j] += bf2f(p1[j]); }
    }
    if (q < end) {
      uint4 u0 = *(const uint4*)&ebuf[(size_t)elist[q] * 128 + c * 8];
      const unsigned short* p0 = (const unsigned short*)&u0;
#pragma unroll
      for (int j = 0; j < 8; j++) a0[j] += bf2f(p0[j]);
    }
    union { uint4 u; unsigned short s[8]; } t;
#pragma unroll
    for (int j = 0; j < 8; j++) t.s[j] = f2bf(a0[j] + a1[j]);
    *(uint4*)&AggH[r * 136 + c * 8] = t.u;
  }
  __syncthreads();

  bf16x8 aa[4];
#pragma unroll
  for (int kt = 0; kt < 4; kt++)
    aa[kt] = *(const bf16x8*)&AggH[(wid * 16 + l15) * 136 + kt * 32 + l4 * 8];

  // ---- GEMM1: 4 phases (K=256) ----
  f32x4 acc1[8] = {};
#pragma unroll
  for (int p = 0; p < 4; ++p) {
    __syncthreads();
    stage((p + 1) & 1, (p < 3) ? (W1T + (p + 1) * 8192) : W2T);
#pragma unroll
    for (int s = 0; s < 2; s++) {
      bf16x8 a = (p < 2) ? av[2 * p + s] : aa[2 * (p - 2) + s];
#pragma unroll
      for (int ct = 0; ct < 8; ct++) {
        bf16x8 b = *(const bf16x8*)&Wb[p & 1][(s * 128 + ct * 16 + l15) * 32 + l4 * 8];
        acc1[ct] = __builtin_amdgcn_mfma_f32_16x16x32_bf16(a, b, acc1[ct], 0, 0, 0);
      }
    }
  }

  // bias1 + relu -> H1 (reuse AggH; wave-own rows), hf frags
#pragma unroll
  for (int ct = 0; ct < 8; ct++) {
    float bb = b1[ct * 16 + l15];
#pragma unroll
    for (int r = 0; r < 4; r++) {
      float h = fmaxf(acc1[ct][r] + bb, 0.f);
      AggH[(wid * 16 + l4 * 4 + r) * 136 + ct * 16 + l15] = f2bf(h);
    }
  }
  bf16x8 hf[4];
#pragma unroll
  for (int kt = 0; kt < 4; kt++)
    hf[kt] = *(const bf16x8*)&AggH[(wid * 16 + l15) * 136 + kt * 32 + l4 * 8];

  // ---- GEMM2: 2 phases ----
  f32x4 acc2[8] = {};
#pragma unroll
  for (int p = 4; p < 6; ++p) {
    __syncthreads();
    if (p < 5) stage((p + 1) & 1, W2T + 8192);
#pragma unroll
    for (int s = 0; s < 2; s++)
#pragma unroll
      for (int ct = 0; ct < 8; ct++) {
        bf16x8 b = *(const bf16x8*)&Wb[p & 1][(s * 128 + ct * 16 + l15) * 32 + l4 * 8];
        acc2[ct] = __builtin_amdgcn_mfma_f32_16x16x32_bf16(hf[2 * (p - 4) + s], b, acc2[ct], 0, 0, 0);
      }
  }

  // ---- bias2 + residual(v) + LN ----
  float s0[4] = {0, 0, 0, 0}, s1v[4] = {0, 0, 0, 0};
#pragma unroll
  for (int ct = 0; ct < 8; ct++) {
    float bb = b2[ct * 16 + l15];
#pragma unroll
    for (int r = 0; r < 4; r++) {
      int rr = row0 + wid * 16 + l4 * 4 + r;
      float x = acc2[ct][r] + bb + bf2f(vbuf[(size_t)rr * 128 + ct * 16 + l15]);
      acc2[ct][r] = x;
      s0[r] += x;
      s1v[r] += x * x;
    }
  }
#pragma unroll
  for (int m = 1; m < 16; m <<= 1)
#pragma unroll
    for (int r = 0; r < 4; r++) {
      s0[r] += __shfl_xor(s0[r], m, 64);
      s1v[r] += __shfl_xor(s1v[r], m, 64);
    }
#pragma unroll
  for (int ct = 0; ct < 8; ct++) {
    float gsc = lng[ct * 16 + l15], bsc = lnb[ct * 16 + l15];
#pragma unroll
    for (int r = 0; r < 4; r++) {
      float mean = s0[r] * (1.f / 128.f);
      float var = s1v[r] * (1.f / 128.f) - mean * mean;
      float y = (acc2[ct][r] - mean) * rsqrtf(var + 1e-5f) * gsc + bsc;
      AggH[(wid * 16 + l4 * 4 + r) * 136 + ct * 16 + l15] = f2bf(y);
    }
  }
#pragma unroll
  for (int i = 0; i < 4; i++) {
    int j = lane + i * 64;
    int r = j >> 4, ch = j & 15;
    *(uint4*)&vbuf[(size_t)(row0 + wid * 16 + r) * 128 + ch * 8] =
        *(const uint4*)&AggH[(wid * 16 + r) * 136 + ch * 8];
  }
}

// ------------------ encoder MLP (K=32 padded input, no residual) -------------
__global__ __launch_bounds__(256) void k_enc(const unsigned short* __restrict__ Xbuf,
                                             const unsigned short* __restrict__ W1T,
                                             const float* __restrict__ b1,
                                             const unsigned short* __restrict__ W2T,
                                             const float* __restrict__ b2,
                                             const float* __restrict__ lng,
                                             const float* __restrict__ lnb,
                                             unsigned short* __restrict__ outbuf) {
  __shared__ __align__(16) unsigned short Xt[64 * 40];
  __shared__ __align__(16) unsigned short H1[64 * 136];
  const int tid = threadIdx.x;
  const int row0 = blockIdx.x * 64;
  {
    int r = tid >> 2, c = tid & 3;
    *(uint4*)&Xt[r * 40 + c * 8] = *(const uint4*)&Xbuf[(size_t)(row0 + r) * 32 + c * 8];
  }
  __syncthreads();
  const int lane = tid & 63, wid = tid >> 6;
  const int l4 = lane >> 4, l15 = lane & 15;

  f32x4 acc1[8] = {};
  bf16x8 a = *(const bf16x8*)&Xt[(wid * 16 + l15) * 40 + l4 * 8];
#pragma unroll
  for (int ct = 0; ct < 8; ct++) {
    bf16x8 b = *(const bf16x8*)&W1T[(ct * 16 + l15) * 32 + l4 * 8];
    acc1[ct] = __builtin_amdgcn_mfma_f32_16x16x32_bf16(a, b, acc1[ct], 0, 0, 0);
  }
#pragma unroll
  for (int ct = 0; ct < 8; ct++) {
    float bb = b1[ct * 16 + l15];
#pragma unroll
    for (int r = 0; r < 4; r++) {
      float h = fmaxf(acc1[ct][r] + bb, 0.f);
      H1[(wid * 16 + l4 * 4 + r) * 136 + ct * 16 + l15] = f2bf(h);
    }
  }
  bf16x8 hf[4];
#pragma unroll
  for (int kt = 0; kt < 4; kt++)
    hf[kt] = *(const bf16x8*)&H1[(wid * 16 + l15) * 136 + kt * 32 + l4 * 8];
  f32x4 acc2[8] = {};
#pragma unroll
  for (int kt = 0; kt < 4; kt++) {
#pragma unroll
    for (int ct = 0; ct < 8; ct++) {
      bf16x8 b = *(const bf16x8*)&W2T[kt * 4096 + (ct * 16 + l15) * 32 + l4 * 8];
      acc2[ct] = __builtin_amdgcn_mfma_f32_16x16x32_bf16(hf[kt], b, acc2[ct], 0, 0, 0);
    }
  }
  float vals[8][4];
  float s0[4] = {0, 0, 0, 0}, s1[4] = {0, 0, 0, 0};
#pragma unroll
  for (int ct = 0; ct < 8; ct++) {
    float bb = b2[ct * 16 + l15];
#pragma unroll
    for (int r = 0; r < 4; r++) {
      float x = acc2[ct][r] + bb;
      vals[ct][r] = x;
      s0[r] += x;
      s1[r] += x * x;
    }
  }
#pragma unroll
  for (int m = 1; m < 16; m <<= 1) {
#pragma unroll
    for (int r = 0; r < 4; r++) {
      s0[r] += __shfl_xor(s0[r], m, 64);
      s1[r] += __shfl_xor(s1[r], m, 64);
    }
  }
#pragma unroll
  for (int ct = 0; ct < 8; ct++) {
    int colc = ct * 16 + l15;
    float g = lng[colc], bb = lnb[colc];
#pragma unroll
    for (int r = 0; r < 4; r++) {
      float mean = s0[r] * (1.f / 128.f);
      float var = s1[r] * (1.f / 128.f) - mean * mean;
      float y = (vals[ct][r] - mean) * rsqrtf(var + 1e-5f) * g + bb;
      H1[(wid * 16 + l4 * 4 + r) * 136 + colc] = f2bf(y);
    }
  }
#pragma unroll
  for (int i = 0; i < 4; i++) {
    int j = lane + i * 64;
    int r = j >> 4, ch = j & 15;
    *(uint4*)&outbuf[(size_t)(row0 + wid * 16 + r) * 128 + ch * 8] =
        *(const uint4*)&H1[(wid * 16 + r) * 136 + ch * 8];
  }
}

__global__ __launch_bounds__(256) void k_decode(const unsigned short* __restrict__ vbuf,
                                                const unsigned short* __restrict__ W1T,
                                                const float* __restrict__ b1,
                                                const float* __restrict__ w2,
                                                const float* __restrict__ b2,
                                                float* __restrict__ out) {
  __shared__ __align__(16) unsigned short Xt[64 * 136];
  __shared__ __align__(16) unsigned short H1[64 * 136];
  const int tid = threadIdx.x;
  const int row0 = blockIdx.x * 64;
  for (int i = tid; i < 64 * 16; i += 256) {
    int r = i >> 4, c = i & 15;
    *(uint4*)&Xt[r * 136 + c * 8] = *(const uint4*)&vbuf[(size_t)(row0 + r) * 128 + c * 8];
  }
  __syncthreads();
  const int lane = tid & 63, wid = tid >> 6;
  const int l4 = lane >> 4, l15 = lane & 15;
  f32x4 acc1[8] = {};
#pragma unroll
  for (int kt = 0; kt < 4; kt++) {
    bf16x8 a = *(const bf16x8*)&Xt[(wid * 16 + l15) * 136 + kt * 32 + l4 * 8];
#pragma unroll
    for (int ct = 0; ct < 8; ct++) {
      bf16x8 b = *(const bf16x8*)&W1T[kt * 4096 + (ct * 16 + l15) * 32 + l4 * 8];
      acc1[ct] = __builtin_amdgcn_mfma_f32_16x16x32_bf16(a, b, acc1[ct], 0, 0, 0);
    }
  }
#pragma unroll
  for (int ct = 0; ct < 8; ct++) {
    float bb = b1[ct * 16 + l15];
#pragma unroll
    for (int r = 0; r < 4; r++) {
      float h = fmaxf(acc1[ct][r] + bb, 0.f);
      H1[(wid * 16 + l4 * 4 + r) * 136 + ct * 16 + l15] = f2bf(h);
    }
  }
  __syncthreads();
  for (int i = tid; i < 64 * 6; i += 256) {
    int r = i / 6, o = i % 6;
    float s = b2[o];
    for (int k = 0; k < 128; k++) s += bf2f(H1[r * 136 + k]) * w2[k * 6 + o];
    out[(size_t)(row0 + r) * 6 + o] = s;
  }
}

extern "C" void kernel_launch(void* const* d_in, const int* in_sizes, int n_in,
                              void* d_out, int out_size, void* d_ws, size_t ws_size,
                              hipStream_t stream) {
  (void)in_sizes; (void)n_in; (void)out_size; (void)ws_size;
  const float* wc = (const float*)d_in[0];
  const float* vf = (const float*)d_in[1];
  const float* mc = (const float*)d_in[2];
  const float* ve_w1 = (const float*)d_in[3];
  const float* ve_b1 = (const float*)d_in[4];
  const float* ve_w2 = (const float*)d_in[5];
  const float* ve_b2 = (const float*)d_in[6];
  const float* ee_w1 = (const float*)d_in[7];
  const float* ee_b1 = (const float*)d_in[8];
  const float* ee_w2 = (const float*)d_in[9];
  const float* ee_b2 = (const float*)d_in[10];
  const float* enc_g = (const float*)d_in[11];
  const float* enc_b = (const float*)d_in[12];
  const float* em_w1 = (const float*)d_in[13];
  const float* em_b1 = (const float*)d_in[14];
  const float* em_w2 = (const float*)d_in[15];
  const float* em_b2 = (const float*)d_in[16];
  const float* em_g = (const float*)d_in[17];
  const float* em_lb = (const float*)d_in[18];
  const float* nm_w1 = (const float*)d_in[19];
  const float* nm_b1 = (const float*)d_in[20];
  const float* nm_w2 = (const float*)d_in[21];
  const float* nm_b2 = (const float*)d_in[22];
  const float* nm_g = (const float*)d_in[23];
  const float* nm_lb = (const float*)d_in[24];
  const float* dec_w1 = (const float*)d_in[25];
  const float* dec_b1 = (const float*)d_in[26];
  const float* dec_w2 = (const float*)d_in[27];
  const float* dec_b2 = (const float*)d_in[28];
  const int* eidx = (const int*)d_in[29];
  const int* sn = (const int*)d_in[30];
  float* dout = (float*)d_out;

  char* w = (char*)d_ws;
  size_t off = 0;
  auto alloc = [&](size_t bytes) {
    char* p = w + off;
    off += (bytes + 255) & ~(size_t)255;
    return p;
  };
  unsigned short* v = (unsigned short*)alloc((size_t)NN * 128 * 2);
  unsigned short* e = (unsigned short*)alloc((size_t)NE * 128 * 2);
  unsigned short* Xve = (unsigned short*)alloc((size_t)NN * 32 * 2);
  unsigned short* Xee = (unsigned short*)alloc((size_t)NE * 32 * 2);
  unsigned short* tve1 = (unsigned short*)alloc(128 * 32 * 2);
  unsigned short* tve2 = (unsigned short*)alloc(128 * 128 * 2);
  unsigned short* tee1 = (unsigned short*)alloc(128 * 32 * 2);
  unsigned short* tee2 = (unsigned short*)alloc(128 * 128 * 2);
  unsigned short* tem1 = (unsigned short*)alloc(128 * 384 * 2);
  unsigned short* tem2 = (unsigned short*)alloc(128 * 128 * 2);
  unsigned short* tnm1 = (unsigned short*)alloc(128 * 256 * 2);
  unsigned short* tnm2 = (unsigned short*)alloc(128 * 128 * 2);
  unsigned short* tdc1 = (unsigned short*)alloc(128 * 128 * 2);
  int* cnt = (int*)alloc(NN * 4);
  int* offsb = (int*)alloc((NN + 1) * 4);
  int* cursor = (int*)alloc(NN * 4);
  int* elist = (int*)alloc((size_t)NE * 4);

  k_zero_i32<<<32, 256, 0, stream>>>(cnt, NN);
  k_pack_all<<<672, 256, 0, stream>>>(ve_w1, tve1, ve_w2, tve2, ee_w1, tee1, ee_w2, tee2,
                                      em_w1, tem1, em_w2, tem2, nm_w1, tnm1, nm_w2, tnm2,
                                      dec_w1, tdc1);
  k_prep_nodes<<<32, 256, 0, stream>>>(sn, vf, Xve);
  k_prep_edges<<<256, 256, 0, stream>>>(eidx, wc, mc, Xee, cnt);
  k_scan<<<1, 1024, 0, stream>>>(cnt, offsb, cursor);
  k_fill<<<256, 256, 0, stream>>>(eidx, cursor, elist);

  k_enc<<<128, 256, 0, stream>>>(Xve, tve1, ve_b1, tve2, ve_b2, enc_g, enc_b, v);
  k_enc<<<1024, 256, 0, stream>>>(Xee, tee1, ee_b1, tee2, ee_b2, enc_g, enc_b, e);
  for (int s = 0; s < 15; ++s) {
    k_edge<<<512, 256, 0, stream>>>(v, e, eidx, tem1, em_b1, tem2, em_b2, em_g, em_lb);
    k_node<<<256, 128, 0, stream>>>(v, e, offsb, elist, tnm1, nm_b1, tnm2, nm_b2, nm_g, nm_lb);
  }
  k_decode<<<128, 256, 0, stream>>>(v, tdc1, dec_b1, dec_w2, dec_b2, dout);
}